// Round 1
// 976.360 us; speedup vs baseline: 1.0665x; 1.0665x over previous
//
#include <hip/hip_runtime.h>
#include <cmath>

#define B_  128
#define T_  512
#define E_  128
#define H_  128
#define G4  512   // 4*H
#define K_  9

// ---------------------------------------------------------------------------
// Kernel 1: input projection GEMM with fused embedding gather.
// proj[b][tc][n] = sum_k embed[sent[b,t]][k] * W_dir[n'][k] + (bih+bhh)[n']
//   n in [0,512)  -> forward  dir, t = t0f + tc
//   n in [512,1024)-> backward dir, t = t0b + tc,  t0b = T - t0f - Tc
// Tile: 64(M) x 64(N) x 128(K, full), 256 threads, 4x4 micro-tile.
// ---------------------------------------------------------------------------
__global__ __launch_bounds__(256, 2)
void proj_gemm(const int* __restrict__ sent, const float* __restrict__ embed,
               const float* __restrict__ Wf, const float* __restrict__ Wb,
               const float* __restrict__ bif, const float* __restrict__ bhf,
               const float* __restrict__ bib, const float* __restrict__ bhb,
               float* __restrict__ proj, int t0f, int Tc)
{
  __shared__ __align__(16) float Al[128 * 64];  // [k][m]
  __shared__ __align__(16) float Bl[128 * 64];  // [k][n]
  const int tid   = threadIdx.x;
  const int ntile = blockIdx.x;            // 0..15
  const int mtile = blockIdx.y;
  const int tpb   = Tc >> 6;               // 64-row tiles per batch element
  const int b     = mtile / tpb;
  const int toff  = (mtile - b * tpb) << 6;
  const int dir   = ntile >> 3;
  const int t0    = dir ? (T_ - t0f - Tc) : t0f;
  const float* __restrict__ W = dir ? Wb : Wf;
  const int n0 = (ntile & 7) << 6;         // row offset inside W (0..448)

  // ---- stage A (gathered embed rows) and B (weight rows), k-major in LDS
  {
    const int r  = tid & 63;
    const int kc = tid >> 6;               // 0..3, each covers 32 k's
    const int t  = t0 + toff + r;
    const int vid = sent[b * T_ + t];
    const float* arow = embed + (size_t)vid * E_ + kc * 32;
    const float* brow = W + (size_t)(n0 + r) * E_ + kc * 32;
#pragma unroll
    for (int q = 0; q < 8; ++q) {
      float4 av = *(const float4*)(arow + q * 4);
      float4 bv = *(const float4*)(brow + q * 4);
      int k0 = kc * 32 + q * 4;
      Al[(k0 + 0) * 64 + r] = av.x; Al[(k0 + 1) * 64 + r] = av.y;
      Al[(k0 + 2) * 64 + r] = av.z; Al[(k0 + 3) * 64 + r] = av.w;
      Bl[(k0 + 0) * 64 + r] = bv.x; Bl[(k0 + 1) * 64 + r] = bv.y;
      Bl[(k0 + 2) * 64 + r] = bv.z; Bl[(k0 + 3) * 64 + r] = bv.w;
    }
  }
  __syncthreads();

  const int mg = tid & 15, ng = tid >> 4;
  float acc[4][4] = {};
#pragma unroll 8
  for (int k = 0; k < 128; ++k) {
    float4 a  = *(const float4*)&Al[k * 64 + mg * 4];
    float4 bb = *(const float4*)&Bl[k * 64 + ng * 4];
    acc[0][0] += a.x * bb.x; acc[0][1] += a.x * bb.y; acc[0][2] += a.x * bb.z; acc[0][3] += a.x * bb.w;
    acc[1][0] += a.y * bb.x; acc[1][1] += a.y * bb.y; acc[1][2] += a.y * bb.z; acc[1][3] += a.y * bb.w;
    acc[2][0] += a.z * bb.x; acc[2][1] += a.z * bb.y; acc[2][2] += a.z * bb.z; acc[2][3] += a.z * bb.w;
    acc[3][0] += a.w * bb.x; acc[3][1] += a.w * bb.y; acc[3][2] += a.w * bb.z; acc[3][3] += a.w * bb.w;
  }

  const float* bi = dir ? bib : bif;
  const float* bh = dir ? bhb : bhf;
  const int nl = ng * 4;
  float4 bias;
  bias.x = bi[n0 + nl + 0] + bh[n0 + nl + 0];
  bias.y = bi[n0 + nl + 1] + bh[n0 + nl + 1];
  bias.z = bi[n0 + nl + 2] + bh[n0 + nl + 2];
  bias.w = bi[n0 + nl + 3] + bh[n0 + nl + 3];
#pragma unroll
  for (int i = 0; i < 4; ++i) {
    const int tloc = toff + mg * 4 + i;
    float4 o;
    o.x = acc[i][0] + bias.x; o.y = acc[i][1] + bias.y;
    o.z = acc[i][2] + bias.z; o.w = acc[i][3] + bias.w;
    *(float4*)&proj[((size_t)(b * Tc + tloc)) * 1024 + dir * G4 + n0 + nl] = o;
  }
}

// ---------------------------------------------------------------------------
// Kernel 2: LSTM recurrence, one block per (direction, batch element).
// 512 threads: thread g owns gate row g (Whh[g][:] in 128 VGPRs).
// h lives in LDS (broadcast reads); c in registers of threads 0..127.
// Packed-sequence semantics: state frozen + output zeroed where t >= len.
//
// R1 changes:
//  - w[] pinned in VGPRs via empty asm (VGPR_Count was 84 < 128 => compiler
//    was re-fetching Whh from L1/L2 every timestep ~ L2-BW bound).
//  - proj load software-pipelined one step ahead (hide ~900cy HBM/L3 latency).
//  - dot product split into 4 accumulators (dep chain 128 -> 32 FMAs).
// ---------------------------------------------------------------------------
__global__ __launch_bounds__(512, 2)
void lstm_chunk(const float* __restrict__ proj,
                const float* __restrict__ Whf, const float* __restrict__ Whb,
                const int* __restrict__ lengths,
                float* __restrict__ hs,
                float* __restrict__ sh, float* __restrict__ sc,
                int t0f, int Tc, int first)
{
  const int dir = blockIdx.x;
  const int b   = blockIdx.y;
  const int tid = threadIdx.x;
  const float* __restrict__ Whh = dir ? Whb : Whf;
  __shared__ __align__(16) float h_lds[H_];
  __shared__ float gates[G4];

  float w[128];
  {
    const float* wr = Whh + (size_t)tid * H_;
#pragma unroll
    for (int k = 0; k < 128; k += 4) {
      float4 v = *(const float4*)(wr + k);
      w[k] = v.x; w[k + 1] = v.y; w[k + 2] = v.z; w[k + 3] = v.w;
    }
  }
  // Pin the weight row in VGPRs: the asm redefines each value, so the
  // compiler cannot rematerialize the global loads inside the step loop.
#pragma unroll
  for (int k = 0; k < 128; ++k) asm volatile("" : "+v"(w[k]));

  const int len = lengths[b];
  const int t0  = dir ? (T_ - t0f - Tc) : t0f;
  float c = 0.f;
  if (tid < H_) {
    if (first) {
      h_lds[tid] = 0.f;
    } else {
      h_lds[tid] = sh[(dir * B_ + b) * H_ + tid];
      c          = sc[(dir * B_ + b) * H_ + tid];
    }
  }
  __syncthreads();

  const float* projp = proj + (size_t)b * Tc * 1024 + dir * G4 + tid;
  // prefetch step 0
  float pv = projp[(size_t)(dir ? (Tc - 1) : 0) * 1024];
  for (int s = 0; s < Tc; ++s) {
    const int tc = dir ? (Tc - 1 - s) : s;   // backward scans t descending
    const int t  = t0 + tc;
    // issue next step's proj load before the compute + barriers (uniform cond)
    float nv = 0.f;
    if (s + 1 < Tc) {
      const int tcn = dir ? (Tc - 2 - s) : (s + 1);
      nv = projp[(size_t)tcn * 1024];
    }
    float a0 = 0.f, a1 = 0.f, a2 = 0.f, a3 = 0.f;
#pragma unroll
    for (int k4 = 0; k4 < 32; ++k4) {
      float4 h4 = *(const float4*)&h_lds[k4 * 4];
      a0 += w[4 * k4 + 0] * h4.x; a1 += w[4 * k4 + 1] * h4.y;
      a2 += w[4 * k4 + 2] * h4.z; a3 += w[4 * k4 + 3] * h4.w;
    }
    float acc = pv + (a0 + a1) + (a2 + a3);
    const int blk = tid >> 7;                // 0:i 1:f 2:g 3:o (torch order)
    gates[tid] = (blk == 2) ? tanhf(acc) : 1.f / (1.f + expf(-acc));
    __syncthreads();
    if (tid < H_) {
      float gi = gates[tid], gf = gates[tid + 128];
      float gg = gates[tid + 256], go = gates[tid + 384];
      float cn = gf * c + gi * gg;
      float hn = go * tanhf(cn);
      bool  m  = (t < len);
      float hold = h_lds[tid];
      c = m ? cn : c;
      h_lds[tid] = m ? hn : hold;
      hs[(size_t)(b * T_ + t) * 256 + dir * H_ + tid] = m ? hn : 0.f;
    }
    __syncthreads();
    pv = nv;
  }
  if (tid < H_) {
    sh[(dir * B_ + b) * H_ + tid] = h_lds[tid];
    sc[(dir * B_ + b) * H_ + tid] = c;
  }
}

// ---------------------------------------------------------------------------
// Kernel 3: emissions em[m][k] = hs[m][:] . W_out[k][:] + b_out[k]
// ---------------------------------------------------------------------------
__global__ __launch_bounds__(256)
void emis_kernel(const float* __restrict__ hs, const float* __restrict__ Wout,
                 const float* __restrict__ bout, float* __restrict__ em)
{
  __shared__ __align__(16) float Wl[K_ * 256];
  const int tid = threadIdx.x;
  for (int i = tid; i < K_ * 256; i += 256) Wl[i] = Wout[i];
  __syncthreads();
  const int m = blockIdx.x * 256 + tid;
  const float* h = hs + (size_t)m * 256;
  float acc[K_] = {};
#pragma unroll 4
  for (int kk = 0; kk < 64; ++kk) {
    float4 h4 = *(const float4*)(h + kk * 4);
#pragma unroll
    for (int k9 = 0; k9 < K_; ++k9) {
      float4 w4 = *(const float4*)&Wl[k9 * 256 + kk * 4];
      acc[k9] += h4.x * w4.x + h4.y * w4.y + h4.z * w4.z + h4.w * w4.w;
    }
  }
#pragma unroll
  for (int k9 = 0; k9 < K_; ++k9) em[(size_t)m * K_ + k9] = acc[k9] + bout[k9];
}

// ---------------------------------------------------------------------------
// Kernel 4: Viterbi decode, one 64-lane wave per batch element.
// Lane k (<9) carries score[k]; shuffles broadcast the score vector.
// Backpointers as uint8 in LDS; padded positions written 0.
// ---------------------------------------------------------------------------
__global__ __launch_bounds__(64)
void viterbi_kernel(const float* __restrict__ em, const int* __restrict__ lengths,
                    const float* __restrict__ st, const float* __restrict__ en,
                    const float* __restrict__ trans, int* __restrict__ tags)
{
  const int b    = blockIdx.x;
  const int lane = threadIdx.x;
  __shared__ unsigned char hist[(T_ - 1) * 16];
  const int len = lengths[b];
  float tr[K_];
#pragma unroll
  for (int j = 0; j < K_; ++j) tr[j] = (lane < K_) ? trans[j * K_ + lane] : 0.f;
  float s = (lane < K_) ? st[lane] + em[(size_t)(b * T_) * K_ + lane] : -1e30f;
  for (int t = 1; t < len; ++t) {
    float best = -1e30f; int bj = 0;
#pragma unroll
    for (int j = 0; j < K_; ++j) {
      float v = __shfl(s, j) + tr[j];
      if (v > best) { best = v; bj = j; }    // strict > == first-max (argmax)
    }
    if (lane < K_) {
      s = best + em[(size_t)(b * T_ + t) * K_ + lane];
      hist[(t - 1) * 16 + lane] = (unsigned char)bj;
    }
  }
  float fs = (lane < K_) ? s + en[lane] : -1e30f;
  float best = -1e30f; int last = 0;
#pragma unroll
  for (int j = 0; j < K_; ++j) {
    float v = __shfl(fs, j);
    if (v > best) { best = v; last = j; }
  }
  __syncthreads();                            // hist visible to lane 0
  if (lane == 0) {
    int tag = last;
    tags[b * T_ + len - 1] = tag;
    for (int t = len - 2; t >= 0; --t) {
      tag = hist[t * 16 + tag];
      tags[b * T_ + t] = tag;
    }
  }
  for (int t = len + lane; t < T_; t += 64) tags[b * T_ + t] = 0;
}

// ---------------------------------------------------------------------------
extern "C" void kernel_launch(void* const* d_in, const int* in_sizes, int n_in,
                              void* d_out, int out_size, void* d_ws, size_t ws_size,
                              hipStream_t stream)
{
  const int*   sent  = (const int*)d_in[0];
  const int*   lens  = (const int*)d_in[1];
  const float* embed = (const float*)d_in[2];
  const float* Wif   = (const float*)d_in[3];
  const float* Whf   = (const float*)d_in[4];
  const float* bif   = (const float*)d_in[5];
  const float* bhf   = (const float*)d_in[6];
  const float* Wib   = (const float*)d_in[7];
  const float* Whb   = (const float*)d_in[8];
  const float* bib   = (const float*)d_in[9];
  const float* bhb   = (const float*)d_in[10];
  const float* Wout  = (const float*)d_in[11];
  const float* bout  = (const float*)d_in[12];
  const float* stt   = (const float*)d_in[13];
  const float* ent   = (const float*)d_in[14];
  const float* trans = (const float*)d_in[15];
  int* tags = (int*)d_out;

  // workspace layout (floats): hs | em | state_h | state_c | proj(chunked)
  float* ws   = (float*)d_ws;
  float* hs   = ws;                                  // B*T*256   (67.1 MB)
  float* em   = hs + (size_t)B_ * T_ * 256;          // B*T*9     ( 2.4 MB)
  float* sh   = em + (size_t)B_ * T_ * K_;           // 2*B*H carry h
  float* sc   = sh + (size_t)2 * B_ * H_;            // 2*B*H carry c
  float* proj = sc + (size_t)2 * B_ * H_;
  const size_t fixed_bytes = (size_t)(proj - ws) * sizeof(float);

  // largest time-chunk whose proj buffer fits the workspace (floor at 64)
  int Tc = 512;
  while (Tc > 64 && fixed_bytes + (size_t)B_ * Tc * 1024 * sizeof(float) > ws_size)
    Tc >>= 1;

  const int nch = T_ / Tc;
  for (int c2 = 0; c2 < nch; ++c2) {
    const int t0f = c2 * Tc;
    dim3 g1(16, B_ * (Tc >> 6));
    hipLaunchKernelGGL(proj_gemm, g1, dim3(256), 0, stream,
                       sent, embed, Wif, Wib, bif, bhf, bib, bhb, proj, t0f, Tc);
    dim3 g2(2, B_);
    hipLaunchKernelGGL(lstm_chunk, g2, dim3(512), 0, stream,
                       proj, Whf, Whb, lens, hs, sh, sc, t0f, Tc, (int)(c2 == 0));
  }
  hipLaunchKernelGGL(emis_kernel, dim3((B_ * T_) / 256), dim3(256), 0, stream,
                     hs, Wout, bout, em);
  hipLaunchKernelGGL(viterbi_kernel, dim3(B_), dim3(64), 0, stream,
                     em, lens, stt, ent, trans, tags);
}

// Round 2
// 967.767 us; speedup vs baseline: 1.0759x; 1.0089x over previous
//
#include <hip/hip_runtime.h>
#include <cmath>

#define B_  128
#define T_  512
#define E_  128
#define H_  128
#define G4  512   // 4*H
#define K_  9

// ---------------------------------------------------------------------------
// Kernel 1: input projection GEMM with fused embedding gather.
// proj[b][tc][n] = sum_k embed[sent[b,t]][k] * W_dir[n'][k] + (bih+bhh)[n']
//   n in [0,512)  -> forward  dir, t = t0f + tc
//   n in [512,1024)-> backward dir, t = t0b + tc,  t0b = T - t0f - Tc
// Tile: 64(M) x 64(N) x 128(K, full), 256 threads, 4x4 micro-tile.
// ---------------------------------------------------------------------------
__global__ __launch_bounds__(256, 2)
void proj_gemm(const int* __restrict__ sent, const float* __restrict__ embed,
               const float* __restrict__ Wf, const float* __restrict__ Wb,
               const float* __restrict__ bif, const float* __restrict__ bhf,
               const float* __restrict__ bib, const float* __restrict__ bhb,
               float* __restrict__ proj, int t0f, int Tc)
{
  __shared__ __align__(16) float Al[128 * 64];  // [k][m]
  __shared__ __align__(16) float Bl[128 * 64];  // [k][n]
  const int tid   = threadIdx.x;
  const int ntile = blockIdx.x;            // 0..15
  const int mtile = blockIdx.y;
  const int tpb   = Tc >> 6;               // 64-row tiles per batch element
  const int b     = mtile / tpb;
  const int toff  = (mtile - b * tpb) << 6;
  const int dir   = ntile >> 3;
  const int t0    = dir ? (T_ - t0f - Tc) : t0f;
  const float* __restrict__ W = dir ? Wb : Wf;
  const int n0 = (ntile & 7) << 6;         // row offset inside W (0..448)

  // ---- stage A (gathered embed rows) and B (weight rows), k-major in LDS
  {
    const int r  = tid & 63;
    const int kc = tid >> 6;               // 0..3, each covers 32 k's
    const int t  = t0 + toff + r;
    const int vid = sent[b * T_ + t];
    const float* arow = embed + (size_t)vid * E_ + kc * 32;
    const float* brow = W + (size_t)(n0 + r) * E_ + kc * 32;
#pragma unroll
    for (int q = 0; q < 8; ++q) {
      float4 av = *(const float4*)(arow + q * 4);
      float4 bv = *(const float4*)(brow + q * 4);
      int k0 = kc * 32 + q * 4;
      Al[(k0 + 0) * 64 + r] = av.x; Al[(k0 + 1) * 64 + r] = av.y;
      Al[(k0 + 2) * 64 + r] = av.z; Al[(k0 + 3) * 64 + r] = av.w;
      Bl[(k0 + 0) * 64 + r] = bv.x; Bl[(k0 + 1) * 64 + r] = bv.y;
      Bl[(k0 + 2) * 64 + r] = bv.z; Bl[(k0 + 3) * 64 + r] = bv.w;
    }
  }
  __syncthreads();

  const int mg = tid & 15, ng = tid >> 4;
  float acc[4][4] = {};
#pragma unroll 8
  for (int k = 0; k < 128; ++k) {
    float4 a  = *(const float4*)&Al[k * 64 + mg * 4];
    float4 bb = *(const float4*)&Bl[k * 64 + ng * 4];
    acc[0][0] += a.x * bb.x; acc[0][1] += a.x * bb.y; acc[0][2] += a.x * bb.z; acc[0][3] += a.x * bb.w;
    acc[1][0] += a.y * bb.x; acc[1][1] += a.y * bb.y; acc[1][2] += a.y * bb.z; acc[1][3] += a.y * bb.w;
    acc[2][0] += a.z * bb.x; acc[2][1] += a.z * bb.y; acc[2][2] += a.z * bb.z; acc[2][3] += a.z * bb.w;
    acc[3][0] += a.w * bb.x; acc[3][1] += a.w * bb.y; acc[3][2] += a.w * bb.z; acc[3][3] += a.w * bb.w;
  }

  const float* bi = dir ? bib : bif;
  const float* bh = dir ? bhb : bhf;
  const int nl = ng * 4;
  float4 bias;
  bias.x = bi[n0 + nl + 0] + bh[n0 + nl + 0];
  bias.y = bi[n0 + nl + 1] + bh[n0 + nl + 1];
  bias.z = bi[n0 + nl + 2] + bh[n0 + nl + 2];
  bias.w = bi[n0 + nl + 3] + bh[n0 + nl + 3];
#pragma unroll
  for (int i = 0; i < 4; ++i) {
    const int tloc = toff + mg * 4 + i;
    float4 o;
    o.x = acc[i][0] + bias.x; o.y = acc[i][1] + bias.y;
    o.z = acc[i][2] + bias.z; o.w = acc[i][3] + bias.w;
    *(float4*)&proj[((size_t)(b * Tc + tloc)) * 1024 + dir * G4 + n0 + nl] = o;
  }
}

// ---------------------------------------------------------------------------
// Kernel 2: LSTM recurrence, one block per (direction, batch element).
// 512 threads: thread g owns gate row g (Whh[g][:] in 128 VGPRs).
// h lives in LDS (broadcast reads); c in registers of threads 0..127.
// Packed-sequence semantics: state frozen + output zeroed where t >= len.
//
// R2 change: __launch_bounds__(512, 1).
//   (512,2) promised 4 waves/SIMD -> 128-VGPR cap -> w[128] spilled to
//   scratch (VGPR_Count=84), re-reading 256KB/step/block from L1/L2
//   (~17 GB/iter ~ L2 ceiling). Grid is 256 blocks on 256 CUs, so 1
//   block/CU is all we ever get: (512,1) costs nothing and gives the
//   256-VGPR budget needed to keep the weight row register-resident.
// ---------------------------------------------------------------------------
__global__ __launch_bounds__(512, 1)
void lstm_chunk(const float* __restrict__ proj,
                const float* __restrict__ Whf, const float* __restrict__ Whb,
                const int* __restrict__ lengths,
                float* __restrict__ hs,
                float* __restrict__ sh, float* __restrict__ sc,
                int t0f, int Tc, int first)
{
  const int dir = blockIdx.x;
  const int b   = blockIdx.y;
  const int tid = threadIdx.x;
  const float* __restrict__ Whh = dir ? Whb : Whf;
  __shared__ __align__(16) float h_lds[H_];
  __shared__ float gates[G4];

  float w[128];
  {
    const float* wr = Whh + (size_t)tid * H_;
#pragma unroll
    for (int k = 0; k < 128; k += 4) {
      float4 v = *(const float4*)(wr + k);
      w[k] = v.x; w[k + 1] = v.y; w[k + 2] = v.z; w[k + 3] = v.w;
    }
  }
  // Pin the weight row in VGPRs (guards against rematerialized global loads).
#pragma unroll
  for (int k = 0; k < 128; ++k) asm volatile("" : "+v"(w[k]));

  const int len = lengths[b];
  const int t0  = dir ? (T_ - t0f - Tc) : t0f;
  float c = 0.f;
  if (tid < H_) {
    if (first) {
      h_lds[tid] = 0.f;
    } else {
      h_lds[tid] = sh[(dir * B_ + b) * H_ + tid];
      c          = sc[(dir * B_ + b) * H_ + tid];
    }
  }
  __syncthreads();

  const float* projp = proj + (size_t)b * Tc * 1024 + dir * G4 + tid;
  // prefetch step 0
  float pv = projp[(size_t)(dir ? (Tc - 1) : 0) * 1024];
  for (int s = 0; s < Tc; ++s) {
    const int tc = dir ? (Tc - 1 - s) : s;   // backward scans t descending
    const int t  = t0 + tc;
    // issue next step's proj load before the compute + barriers (uniform cond)
    float nv = 0.f;
    if (s + 1 < Tc) {
      const int tcn = dir ? (Tc - 2 - s) : (s + 1);
      nv = projp[(size_t)tcn * 1024];
    }
    float a0 = 0.f, a1 = 0.f, a2 = 0.f, a3 = 0.f;
#pragma unroll
    for (int k4 = 0; k4 < 32; ++k4) {
      float4 h4 = *(const float4*)&h_lds[k4 * 4];
      a0 += w[4 * k4 + 0] * h4.x; a1 += w[4 * k4 + 1] * h4.y;
      a2 += w[4 * k4 + 2] * h4.z; a3 += w[4 * k4 + 3] * h4.w;
    }
    float acc = pv + (a0 + a1) + (a2 + a3);
    const int blk = tid >> 7;                // 0:i 1:f 2:g 3:o (torch order)
    gates[tid] = (blk == 2) ? tanhf(acc) : 1.f / (1.f + expf(-acc));
    __syncthreads();
    if (tid < H_) {
      float gi = gates[tid], gf = gates[tid + 128];
      float gg = gates[tid + 256], go = gates[tid + 384];
      float cn = gf * c + gi * gg;
      float hn = go * tanhf(cn);
      bool  m  = (t < len);
      float hold = h_lds[tid];
      c = m ? cn : c;
      h_lds[tid] = m ? hn : hold;
      hs[(size_t)(b * T_ + t) * 256 + dir * H_ + tid] = m ? hn : 0.f;
    }
    __syncthreads();
    pv = nv;
  }
  if (tid < H_) {
    sh[(dir * B_ + b) * H_ + tid] = h_lds[tid];
    sc[(dir * B_ + b) * H_ + tid] = c;
  }
}

// ---------------------------------------------------------------------------
// Kernel 3: emissions em[m][k] = hs[m][:] . W_out[k][:] + b_out[k]
// ---------------------------------------------------------------------------
__global__ __launch_bounds__(256)
void emis_kernel(const float* __restrict__ hs, const float* __restrict__ Wout,
                 const float* __restrict__ bout, float* __restrict__ em)
{
  __shared__ __align__(16) float Wl[K_ * 256];
  const int tid = threadIdx.x;
  for (int i = tid; i < K_ * 256; i += 256) Wl[i] = Wout[i];
  __syncthreads();
  const int m = blockIdx.x * 256 + tid;
  const float* h = hs + (size_t)m * 256;
  float acc[K_] = {};
#pragma unroll 4
  for (int kk = 0; kk < 64; ++kk) {
    float4 h4 = *(const float4*)(h + kk * 4);
#pragma unroll
    for (int k9 = 0; k9 < K_; ++k9) {
      float4 w4 = *(const float4*)&Wl[k9 * 256 + kk * 4];
      acc[k9] += h4.x * w4.x + h4.y * w4.y + h4.z * w4.z + h4.w * w4.w;
    }
  }
#pragma unroll
  for (int k9 = 0; k9 < K_; ++k9) em[(size_t)m * K_ + k9] = acc[k9] + bout[k9];
}

// ---------------------------------------------------------------------------
// Kernel 4: Viterbi decode, one 64-lane wave per batch element.
// Lane k (<9) carries score[k]; shuffles broadcast the score vector.
// Backpointers as uint8 in LDS; padded positions written 0.
// ---------------------------------------------------------------------------
__global__ __launch_bounds__(64)
void viterbi_kernel(const float* __restrict__ em, const int* __restrict__ lengths,
                    const float* __restrict__ st, const float* __restrict__ en,
                    const float* __restrict__ trans, int* __restrict__ tags)
{
  const int b    = blockIdx.x;
  const int lane = threadIdx.x;
  __shared__ unsigned char hist[(T_ - 1) * 16];
  const int len = lengths[b];
  float tr[K_];
#pragma unroll
  for (int j = 0; j < K_; ++j) tr[j] = (lane < K_) ? trans[j * K_ + lane] : 0.f;
  float s = (lane < K_) ? st[lane] + em[(size_t)(b * T_) * K_ + lane] : -1e30f;
  for (int t = 1; t < len; ++t) {
    float best = -1e30f; int bj = 0;
#pragma unroll
    for (int j = 0; j < K_; ++j) {
      float v = __shfl(s, j) + tr[j];
      if (v > best) { best = v; bj = j; }    // strict > == first-max (argmax)
    }
    if (lane < K_) {
      s = best + em[(size_t)(b * T_ + t) * K_ + lane];
      hist[(t - 1) * 16 + lane] = (unsigned char)bj;
    }
  }
  float fs = (lane < K_) ? s + en[lane] : -1e30f;
  float best = -1e30f; int last = 0;
#pragma unroll
  for (int j = 0; j < K_; ++j) {
    float v = __shfl(fs, j);
    if (v > best) { best = v; last = j; }
  }
  __syncthreads();                            // hist visible to lane 0
  if (lane == 0) {
    int tag = last;
    tags[b * T_ + len - 1] = tag;
    for (int t = len - 2; t >= 0; --t) {
      tag = hist[t * 16 + tag];
      tags[b * T_ + t] = tag;
    }
  }
  for (int t = len + lane; t < T_; t += 64) tags[b * T_ + t] = 0;
}

// ---------------------------------------------------------------------------
extern "C" void kernel_launch(void* const* d_in, const int* in_sizes, int n_in,
                              void* d_out, int out_size, void* d_ws, size_t ws_size,
                              hipStream_t stream)
{
  const int*   sent  = (const int*)d_in[0];
  const int*   lens  = (const int*)d_in[1];
  const float* embed = (const float*)d_in[2];
  const float* Wif   = (const float*)d_in[3];
  const float* Whf   = (const float*)d_in[4];
  const float* bif   = (const float*)d_in[5];
  const float* bhf   = (const float*)d_in[6];
  const float* Wib   = (const float*)d_in[7];
  const float* Whb   = (const float*)d_in[8];
  const float* bib   = (const float*)d_in[9];
  const float* bhb   = (const float*)d_in[10];
  const float* Wout  = (const float*)d_in[11];
  const float* bout  = (const float*)d_in[12];
  const float* stt   = (const float*)d_in[13];
  const float* ent   = (const float*)d_in[14];
  const float* trans = (const float*)d_in[15];
  int* tags = (int*)d_out;

  // workspace layout (floats): hs | em | state_h | state_c | proj(chunked)
  float* ws   = (float*)d_ws;
  float* hs   = ws;                                  // B*T*256   (67.1 MB)
  float* em   = hs + (size_t)B_ * T_ * 256;          // B*T*9     ( 2.4 MB)
  float* sh   = em + (size_t)B_ * T_ * K_;           // 2*B*H carry h
  float* sc   = sh + (size_t)2 * B_ * H_;            // 2*B*H carry c
  float* proj = sc + (size_t)2 * B_ * H_;
  const size_t fixed_bytes = (size_t)(proj - ws) * sizeof(float);

  // largest time-chunk whose proj buffer fits the workspace (floor at 64)
  int Tc = 512;
  while (Tc > 64 && fixed_bytes + (size_t)B_ * Tc * 1024 * sizeof(float) > ws_size)
    Tc >>= 1;

  const int nch = T_ / Tc;
  for (int c2 = 0; c2 < nch; ++c2) {
    const int t0f = c2 * Tc;
    dim3 g1(16, B_ * (Tc >> 6));
    hipLaunchKernelGGL(proj_gemm, g1, dim3(256), 0, stream,
                       sent, embed, Wif, Wib, bif, bhf, bib, bhb, proj, t0f, Tc);
    dim3 g2(2, B_);
    hipLaunchKernelGGL(lstm_chunk, g2, dim3(512), 0, stream,
                       proj, Whf, Whb, lens, hs, sh, sc, t0f, Tc, (int)(c2 == 0));
  }
  hipLaunchKernelGGL(emis_kernel, dim3((B_ * T_) / 256), dim3(256), 0, stream,
                     hs, Wout, bout, em);
  hipLaunchKernelGGL(viterbi_kernel, dim3(B_), dim3(64), 0, stream,
                     em, lens, stt, ent, trans, tags);
}